// Round 9
// baseline (249.769 us; speedup 1.0000x reference)
//
#include <hip/hip_runtime.h>
#include <hip/hip_bf16.h>
#include <math.h>
#include <stdint.h>

typedef __bf16 bf16;
typedef __bf16 bf16x8 __attribute__((ext_vector_type(8)));
typedef __bf16 bf16x4v __attribute__((ext_vector_type(4)));
typedef float f32x4 __attribute__((ext_vector_type(4)));

#define NHEADS 4
#define DM 768
#define DB 64
#define HD 192
#define BATCH 8
#define SEQ 1024
#define MROWS 8192
#define SCALE 0.07216878364870323f

__device__ __forceinline__ void gld_lds16(const void* g, void* l) {
  __builtin_amdgcn_global_load_lds(
      (__attribute__((address_space(1))) void*)(void*)g,
      (__attribute__((address_space(3))) void*)l, 16, 0, 0);
}

// ---------------- fused weight prep: 4 transposes in one launch ----------------
// id<2304: Wq(768x768)->WT0 ; <4608: Wv->WT1 ; <4800: Wk(64x768)->WT2 ; else Wo->WT3
__global__ __launch_bounds__(256) void prep_weights(
    const float* __restrict__ Wq, const float* __restrict__ Wv,
    const float* __restrict__ Wk, const float* __restrict__ Wo,
    bf16* __restrict__ WT0, bf16* __restrict__ WT1,
    bf16* __restrict__ WT2, bf16* __restrict__ WT3) {
  int id = blockIdx.x;
  const float* W;
  bf16* WT;
  int K, base;
  if (id < 2304)      { W = Wq; WT = WT0; K = DM; base = 0; }
  else if (id < 4608) { W = Wv; WT = WT1; K = DM; base = 2304; }
  else if (id < 4800) { W = Wk; WT = WT2; K = DB; base = 4608; }
  else                { W = Wo; WT = WT3; K = DM; base = 4800; }
  long idx = (long)(id - base) * 256 + threadIdx.x;
  if (idx >= (long)K * DM) return;
  int k = (int)(idx % K);
  int n = (int)(idx / K);
  WT[(long)n * K + k] = (bf16)W[(long)k * DM + n];
}

// ---------------- bias MLP ----------------
__global__ __launch_bounds__(256) void bias_mlp(const float* __restrict__ bloom,
                                                const float* __restrict__ Wb1,
                                                const float* __restrict__ bb1,
                                                const float* __restrict__ Wb2,
                                                const float* __restrict__ bb2,
                                                float* __restrict__ biasarr) {
  int idx = blockIdx.x * blockDim.x + threadIdx.x;
  if (idx >= MROWS) return;
  const float* x = bloom + (long)idx * DB;
  float h[8];
#pragma unroll
  for (int j = 0; j < 8; ++j) h[j] = bb1[j];
  for (int k = 0; k < DB; ++k) {
    float xv = x[k];
#pragma unroll
    for (int j = 0; j < 8; ++j) h[j] = fmaf(xv, Wb1[k * 8 + j], h[j]);
  }
#pragma unroll
  for (int j = 0; j < 8; ++j) {
    float a = h[j];
    h[j] = 0.5f * a * (1.0f + erff(a * 0.7071067811865476f));
  }
  int b = idx >> 10, s = idx & 1023;
#pragma unroll
  for (int o = 0; o < 4; ++o) {
    float a = bb2[o];
#pragma unroll
    for (int j = 0; j < 8; ++j) a = fmaf(h[j], Wb2[j * 4 + o], a);
    biasarr[((long)(b * 4 + o) << 10) + s] = a;
  }
}

// ---------------- row-sum + normalize (streaming, full occupancy) ----------------
// 8192 blocks x 256 thr: one wave per row of 1024. E bf16 (L3-hot) -> attn f32 (nt) + inv.
__global__ __launch_bounds__(256) void rowsum_scale_bf16(const bf16* __restrict__ E,
                                                         float* __restrict__ attn,
                                                         float* __restrict__ inv) {
  const int row = blockIdx.x * 4 + (threadIdx.x >> 6);
  const int lane = threadIdx.x & 63;
  const bf16* er = E + ((long)row << 10);
  float* ar = attn + ((long)row << 10);
  bf16x8 v0 = *(const bf16x8*)&er[lane * 8];
  bf16x8 v1 = *(const bf16x8*)&er[512 + lane * 8];
  float f[16];
  float s = 0.0f;
#pragma unroll
  for (int e = 0; e < 8; ++e) { f[e] = (float)v0[e]; f[8 + e] = (float)v1[e]; }
#pragma unroll
  for (int e = 0; e < 16; ++e) s += f[e];
  for (int d = 1; d < 64; d <<= 1) s += __shfl_xor(s, d);
  float iv = 1.0f / s;
  if (lane == 0) inv[row] = iv;
  f32x4 w;
  w[0] = f[0] * iv; w[1] = f[1] * iv; w[2] = f[2] * iv; w[3] = f[3] * iv;
  __builtin_nontemporal_store(w, (f32x4*)&ar[lane * 8]);
  w[0] = f[4] * iv; w[1] = f[5] * iv; w[2] = f[6] * iv; w[3] = f[7] * iv;
  __builtin_nontemporal_store(w, (f32x4*)&ar[lane * 8 + 4]);
  w[0] = f[8] * iv; w[1] = f[9] * iv; w[2] = f[10] * iv; w[3] = f[11] * iv;
  __builtin_nontemporal_store(w, (f32x4*)&ar[512 + lane * 8]);
  w[0] = f[12] * iv; w[1] = f[13] * iv; w[2] = f[14] * iv; w[3] = f[15] * iv;
  __builtin_nontemporal_store(w, (f32x4*)&ar[512 + lane * 8 + 4]);
}

// fallback: E was written f32 into attn; normalize in place.
__global__ __launch_bounds__(256) void rowsum_scale_f32(float* __restrict__ attn) {
  const int row = blockIdx.x * 4 + (threadIdx.x >> 6);
  const int lane = threadIdx.x & 63;
  float* ar = attn + ((long)row << 10);
  f32x4 v[4];
#pragma unroll
  for (int i = 0; i < 4; ++i) v[i] = *(const f32x4*)&ar[i * 256 + lane * 4];
  float s = 0.0f;
#pragma unroll
  for (int i = 0; i < 4; ++i)
#pragma unroll
    for (int j = 0; j < 4; ++j) s += v[i][j];
  for (int d = 1; d < 64; d <<= 1) s += __shfl_xor(s, d);
  float iv = 1.0f / s;
#pragma unroll
  for (int i = 0; i < 4; ++i) {
#pragma unroll
    for (int j = 0; j < 4; ++j) v[i][j] *= iv;
    *(f32x4*)&ar[i * 256 + lane * 4] = v[i];
  }
}

// ---------------- GEMM (A [M,K], BT row-major [N,K] bf16) ----------------
// A is f32 (converted during staging) for MODE 0 (K proj), 6 (QV proj), 5 (PV fallback).
// MODE 0: A=Xb f32 lda=64; bf16 out natural +cb1          (K projection)
// MODE 6: A=Xd f32 lda=768; fused QV: ng<768 -> Q (+cb1); else V scatter-T (+cb2)
// MODE 2: E = exp(v*SCALE + bias) bf16, batched            (scores, 2048 blocks)
// MODE 7: like 2 but f32 out into attn                     (fallback)
// MODE 3: A bf16 batched (E), out bf16 ctx * inv[row]      (PV fast, 512 blocks)
// MODE 5: A f32 batched (normalized attn), out bf16 ctx    (PV fallback)
// MODE 4: f32 out = acc + cb1 + resid                      (final x)
template <int MODE>
__global__ __launch_bounds__(256) void gemm_bt(
    const bf16* __restrict__ A, int lda,
    const bf16* __restrict__ BT, int ldb,
    const float* __restrict__ Af,
    int M, int N, int Kd,
    const float* __restrict__ cb1,
    const float* __restrict__ cb2,
    const float* __restrict__ resid,
    void* __restrict__ out, void* __restrict__ out2) {
  __shared__ __attribute__((aligned(16))) bf16 aL[128 * 32];
  __shared__ __attribute__((aligned(16))) bf16 bL[128 * 32];
  const int tid = threadIdx.x;
  const int lane = tid & 63;
  const int wid = tid >> 6;
  const int wr = wid >> 1, wc = wid & 1;
  int bx, by, bz;
  if constexpr (MODE == 2 || MODE == 7) {
    int idd = blockIdx.x;
    bz = idd & 31;
    int t = idd >> 5;
    bx = t & 7;
    by = t >> 3;
  } else if constexpr (MODE == 3 || MODE == 5) {
    int idd = blockIdx.x;
    bz = idd & 31;
    bx = (idd >> 5) & 1;
    by = idd >> 6;
  } else {
    bx = blockIdx.x; by = blockIdx.y; bz = 0;
  }
  const int m0 = by * 128, n0 = bx * 128;

  const bf16* Ab = A;
  const bf16* Bb = BT;
  const float* Afb = Af;
  if constexpr (MODE == 2 || MODE == 7) {
    long o = ((long)((bz >> 2) * SEQ)) * DM + (long)(bz & 3) * HD;
    Ab = A + o;
    Bb = BT + o;
  }
  if constexpr (MODE == 3) {
    Ab = A + ((long)bz << 20);
    Bb = BT + (((long)((bz >> 2) * DM + (bz & 3) * HD)) << 10);
  }
  if constexpr (MODE == 5) {
    Bb = BT + (((long)((bz >> 2) * DM + (bz & 3) * HD)) << 10);
    Afb = Af + ((long)bz << 20);
  }
  constexpr bool AF32 = (MODE == 0 || MODE == 5 || MODE == 6);

  f32x4 acc[4][4] = {};

  for (int k0 = 0; k0 < Kd; k0 += 32) {
    if constexpr (AF32) {
#pragma unroll
      for (int p = 0; p < 2; ++p) {
        int f = (p * 256 + tid) * 8;
        int row = f >> 5, col = f & 31;
        const float* g = Afb + (long)(m0 + row) * lda + k0 + col;
        f32x4 x0 = *(const f32x4*)g;
        f32x4 x1 = *(const f32x4*)(g + 4);
        bf16x8 t;
        t[0] = (bf16)x0[0]; t[1] = (bf16)x0[1]; t[2] = (bf16)x0[2]; t[3] = (bf16)x0[3];
        t[4] = (bf16)x1[0]; t[5] = (bf16)x1[1]; t[6] = (bf16)x1[2]; t[7] = (bf16)x1[3];
        *(bf16x8*)&aL[f] = t;
      }
    } else {
#pragma unroll
      for (int p = 0; p < 2; ++p) {
        int f = (p * 256 + tid) * 8;
        int row = f >> 5, col = f & 31;
        gld_lds16(Ab + (long)(m0 + row) * lda + k0 + col, &aL[f]);
      }
    }
#pragma unroll
    for (int p = 0; p < 2; ++p) {
      int f = (p * 256 + tid) * 8;
      int row = f >> 5, col = f & 31;
      int nn = n0 + row;
      nn = nn < N ? nn : N - 1;
      gld_lds16(Bb + (long)nn * ldb + k0 + col, &bL[f]);
    }
    __syncthreads();

    const int rsel = lane & 15, ksel = (lane >> 4) * 8;
    bf16x8 af[4], bfr[4];
#pragma unroll
    for (int m = 0; m < 4; ++m)
      af[m] = *(const bf16x8*)&aL[(wr * 64 + m * 16 + rsel) * 32 + ksel];
#pragma unroll
    for (int n = 0; n < 4; ++n)
      bfr[n] = *(const bf16x8*)&bL[(wc * 64 + n * 16 + rsel) * 32 + ksel];
#pragma unroll
    for (int m = 0; m < 4; ++m)
#pragma unroll
      for (int n = 0; n < 4; ++n)
        acc[m][n] = __builtin_amdgcn_mfma_f32_16x16x32_bf16(af[m], bfr[n], acc[m][n], 0, 0, 0);
    __syncthreads();
  }

  const int rl = (lane >> 4) * 4, cl = lane & 15;
#pragma unroll
  for (int m = 0; m < 4; ++m) {
#pragma unroll
    for (int n = 0; n < 4; ++n) {
      int ng = n0 + wc * 64 + n * 16 + cl;
      if (ng >= N) continue;
#pragma unroll
      for (int j = 0; j < 4; ++j) {
        int mg = m0 + wr * 64 + m * 16 + rl + j;
        float v = acc[m][n][j];
        if constexpr (MODE == 0) {
          ((bf16*)out)[(long)mg * DM + ng] = (bf16)(v + cb1[ng]);
        } else if constexpr (MODE == 2) {
          ((bf16*)out)[((long)bz << 20) + ((long)mg << 10) + ng] =
              (bf16)__expf(fmaf(v, SCALE, cb2[(bz << 10) + ng]));
        } else if constexpr (MODE == 7) {
          ((float*)out)[((long)bz << 20) + ((long)mg << 10) + ng] =
              __expf(fmaf(v, SCALE, cb2[(bz << 10) + ng]));
        } else if constexpr (MODE == 3) {
          ((bf16*)out)[(long)((bz >> 2) * SEQ + mg) * DM + (bz & 3) * HD + ng] =
              (bf16)(v * cb2[(bz << 10) + mg]);
        } else if constexpr (MODE == 5) {
          ((bf16*)out)[(long)((bz >> 2) * SEQ + mg) * DM + (bz & 3) * HD + ng] = (bf16)v;
        } else if constexpr (MODE == 6) {
          if (ng < DM) {
            ((bf16*)out)[(long)mg * DM + ng] = (bf16)(v + cb1[ng]);
          } else {
            int d = ng - DM;
            int b = mg >> 10, s = mg & 1023;
            ((bf16*)out2)[((long)(b * DM + d) << 10) + s] = (bf16)(v + cb2[d]);
          }
        } else {
          long o = (long)mg * DM + ng;
          ((float*)out)[o] = v + cb1[ng] + resid[o];
        }
      }
    }
  }
}

// ---------------- layernorm (one wave per row of 768, in place) ----------------
__global__ __launch_bounds__(256) void layernorm_rows(float* x, const float* __restrict__ gam,
                                                      const float* __restrict__ bet) {
  int row = blockIdx.x * 4 + (threadIdx.x >> 6);
  int lane = threadIdx.x & 63;
  float* r = x + (long)row * DM;
  f32x4 v[3];
#pragma unroll
  for (int i = 0; i < 3; ++i) v[i] = *(const f32x4*)&r[i * 256 + lane * 4];
  float s = 0.0f, ss = 0.0f;
#pragma unroll
  for (int i = 0; i < 3; ++i)
#pragma unroll
    for (int j = 0; j < 4; ++j) {
      s += v[i][j];
      ss += v[i][j] * v[i][j];
    }
  for (int d = 1; d < 64; d <<= 1) {
    s += __shfl_xor(s, d);
    ss += __shfl_xor(ss, d);
  }
  float mu = s * (1.0f / 768.0f);
  float var = ss * (1.0f / 768.0f) - mu * mu;
  float rs = 1.0f / sqrtf(var + 1e-5f);
#pragma unroll
  for (int i = 0; i < 3; ++i) {
#pragma unroll
    for (int j = 0; j < 4; ++j) {
      int c = i * 256 + lane * 4 + j;
      v[i][j] = (v[i][j] - mu) * rs * gam[c] + bet[c];
    }
    *(f32x4*)&r[i * 256 + lane * 4] = v[i];
  }
}

// ---------------- launcher ----------------
extern "C" void kernel_launch(void* const* d_in, const int* in_sizes, int n_in,
                              void* d_out, int out_size, void* d_ws, size_t ws_size,
                              hipStream_t stream) {
  const float* Xd = (const float*)d_in[0];
  const float* Xb = (const float*)d_in[1];
  const float* Wq = (const float*)d_in[2];
  const float* bq = (const float*)d_in[3];
  const float* Wk = (const float*)d_in[4];
  const float* bk = (const float*)d_in[5];
  const float* Wv = (const float*)d_in[6];
  const float* bv = (const float*)d_in[7];
  const float* Wb1 = (const float*)d_in[8];
  const float* bb1 = (const float*)d_in[9];
  const float* Wb2 = (const float*)d_in[10];
  const float* bb2 = (const float*)d_in[11];
  const float* Wo = (const float*)d_in[12];
  const float* bo = (const float*)d_in[13];
  const float* lng = (const float*)d_in[14];
  const float* lnb = (const float*)d_in[15];

  float* y = (float*)d_out;                  // 8192*768 f32
  float* attn = y + (long)MROWS * DM;        // 32*1024*1024 f32

  char* w = (char*)d_ws;
  bf16* WqvT = (bf16*)w; w += (long)2 * DM * DM * 2;   // [1536][768]
  bf16* WkT = (bf16*)w; w += (long)DM * DB * 2;
  bf16* WoT = (bf16*)w; w += (long)DM * DM * 2;
  bf16* Qb = (bf16*)w; w += (long)MROWS * DM * 2;
  bf16* Kb = (bf16*)w; w += (long)MROWS * DM * 2;
  bf16* VTb = (bf16*)w; w += (long)MROWS * DM * 2;
  bf16* ctxb = (bf16*)w; w += (long)MROWS * DM * 2;
  float* biasarr = (float*)w; w += (long)BATCH * NHEADS * SEQ * 4;
  float* inv = (float*)w; w += (long)32 * SEQ * 4;
  bf16* Sb = (bf16*)w; w += (long)32 * SEQ * SEQ * 2;  // 64 MB E buffer
  const bool useS = ((size_t)(w - (char*)d_ws)) <= ws_size;

  dim3 blk(256);
  // weight transposes (1 launch) + bias MLP
  prep_weights<<<7104, blk, 0, stream>>>(Wq, Wv, Wk, Wo,
                                         WqvT, WqvT + (long)DM * DM, WkT, WoT);
  bias_mlp<<<32, blk, 0, stream>>>(Xb, Wb1, bb1, Wb2, bb2, biasarr);

  // K = Xb @ Wk + bk  (A = Xb f32, converted in staging)
  gemm_bt<0><<<dim3(6, 64, 1), blk, 0, stream>>>(nullptr, DB, WkT, DB, Xb, MROWS, DM, DB,
                                                 bk, nullptr, nullptr, Kb, nullptr);
  // [Q | V] = Xd @ [Wq | Wv]  (A = Xd f32): Q natural -> Qb, V scatter-T -> VTb
  gemm_bt<6><<<dim3(12, 64, 1), blk, 0, stream>>>(nullptr, DM, WqvT, DM, Xd, MROWS, 2 * DM, DM,
                                                  bq, bv, nullptr, Qb, VTb);
  if (useS) {
    // E = exp(QK^T*scale + bias) bf16, 2048 blocks
    gemm_bt<2><<<2048, blk, 0, stream>>>(Qb, DM, Kb, DM, nullptr, SEQ, SEQ, HD,
                                         nullptr, biasarr, nullptr, Sb, nullptr);
    // row sums -> attn f32 (nt stores) + inv
    rowsum_scale_bf16<<<8192, blk, 0, stream>>>(Sb, attn, inv);
    // ctx = (E @ V) * inv
    gemm_bt<3><<<512, blk, 0, stream>>>(Sb, SEQ, VTb, SEQ, nullptr, SEQ, HD, SEQ,
                                        nullptr, inv, nullptr, ctxb, nullptr);
  } else {
    gemm_bt<7><<<2048, blk, 0, stream>>>(Qb, DM, Kb, DM, nullptr, SEQ, SEQ, HD,
                                         nullptr, biasarr, nullptr, attn, nullptr);
    rowsum_scale_f32<<<8192, blk, 0, stream>>>(attn);
    gemm_bt<5><<<512, blk, 0, stream>>>(nullptr, SEQ, VTb, SEQ, attn, SEQ, HD, SEQ,
                                        nullptr, nullptr, nullptr, ctxb, nullptr);
  }
  // x = ctx @ Wo + bo + resid -> y region, then LN in place
  gemm_bt<4><<<dim3(6, 64, 1), blk, 0, stream>>>(ctxb, DM, WoT, DM, nullptr, MROWS, DM, DM,
                                                 bo, nullptr, Xd, y, nullptr);
  layernorm_rows<<<2048, 256, 0, stream>>>(y, lng, lnb);
}

// Round 10
// 244.918 us; speedup vs baseline: 1.0198x; 1.0198x over previous
//
#include <hip/hip_runtime.h>
#include <hip/hip_bf16.h>
#include <math.h>
#include <stdint.h>

typedef __bf16 bf16;
typedef __bf16 bf16x8 __attribute__((ext_vector_type(8)));
typedef __bf16 bf16x4v __attribute__((ext_vector_type(4)));
typedef float f32x4 __attribute__((ext_vector_type(4)));

#define NHEADS 4
#define DM 768
#define DB 64
#define HD 192
#define BATCH 8
#define SEQ 1024
#define MROWS 8192
#define SCALE 0.07216878364870323f

__device__ __forceinline__ void gld_lds16(const void* g, void* l) {
  __builtin_amdgcn_global_load_lds(
      (__attribute__((address_space(1))) void*)(void*)g,
      (__attribute__((address_space(3))) void*)l, 16, 0, 0);
}

// ---------------- converts ----------------
__global__ __launch_bounds__(256) void cvt_f32_bf16(const float* __restrict__ in,
                                                    bf16* __restrict__ out, long n4) {
  long i = (long)blockIdx.x * blockDim.x + threadIdx.x;
  if (i >= n4) return;
  f32x4 v = *(const f32x4*)&in[i * 4];
  bf16x4v t;
  t[0] = (bf16)v[0]; t[1] = (bf16)v[1]; t[2] = (bf16)v[2]; t[3] = (bf16)v[3];
  *(bf16x4v*)&out[i * 4] = t;
}

// ---------------- fused weight prep: 4 transposes in one launch ----------------
__global__ __launch_bounds__(256) void prep_weights(
    const float* __restrict__ Wq, const float* __restrict__ Wv,
    const float* __restrict__ Wk, const float* __restrict__ Wo,
    bf16* __restrict__ WT0, bf16* __restrict__ WT1,
    bf16* __restrict__ WT2, bf16* __restrict__ WT3) {
  int id = blockIdx.x;
  const float* W;
  bf16* WT;
  int K, base;
  if (id < 2304)      { W = Wq; WT = WT0; K = DM; base = 0; }
  else if (id < 4608) { W = Wv; WT = WT1; K = DM; base = 2304; }
  else if (id < 4800) { W = Wk; WT = WT2; K = DB; base = 4608; }
  else                { W = Wo; WT = WT3; K = DM; base = 4800; }
  long idx = (long)(id - base) * 256 + threadIdx.x;
  if (idx >= (long)K * DM) return;
  int k = (int)(idx % K);
  int n = (int)(idx / K);
  WT[(long)n * K + k] = (bf16)W[(long)k * DM + n];
}

// ---------------- bias MLP ----------------
__global__ __launch_bounds__(256) void bias_mlp(const float* __restrict__ bloom,
                                                const float* __restrict__ Wb1,
                                                const float* __restrict__ bb1,
                                                const float* __restrict__ Wb2,
                                                const float* __restrict__ bb2,
                                                float* __restrict__ biasarr) {
  int idx = blockIdx.x * blockDim.x + threadIdx.x;
  if (idx >= MROWS) return;
  const float* x = bloom + (long)idx * DB;
  float h[8];
#pragma unroll
  for (int j = 0; j < 8; ++j) h[j] = bb1[j];
  for (int k = 0; k < DB; ++k) {
    float xv = x[k];
#pragma unroll
    for (int j = 0; j < 8; ++j) h[j] = fmaf(xv, Wb1[k * 8 + j], h[j]);
  }
#pragma unroll
  for (int j = 0; j < 8; ++j) {
    float a = h[j];
    h[j] = 0.5f * a * (1.0f + erff(a * 0.7071067811865476f));
  }
  int b = idx >> 10, s = idx & 1023;
#pragma unroll
  for (int o = 0; o < 4; ++o) {
    float a = bb2[o];
#pragma unroll
    for (int j = 0; j < 8; ++j) a = fmaf(h[j], Wb2[j * 4 + o], a);
    biasarr[((long)(b * 4 + o) << 10) + s] = a;
  }
}

// ---------------- fused scores + bias + softmax (v5: 16 rows, 2 blocks/CU) ----------------
// 2048 blocks x 512 threads. z = id&31 -> XCD-affine K. Block = 16 q-rows.
// 8 waves each own a 128-col slice; acc[8] = 32 f32/lane -> ~110 regs -> 2 blocks/CU.
// LDS K staging + staged coalesced attn write (proven R7 structure, rows 64->16).
__global__ __launch_bounds__(512, 4) void scores_softmax(
    const bf16* __restrict__ Qb, const bf16* __restrict__ Kb,
    const float* __restrict__ biasarr, float* __restrict__ attn) {
  __shared__ __attribute__((aligned(16))) bf16 bL[1024 * 32];  // 64 KB
  const int tid = threadIdx.x;
  const int lane = tid & 63;
  const int wid = tid >> 6;
  const int id = blockIdx.x;
  const int z = id & 31;
  const int m0 = (id >> 5) * 16;
  const int b = z >> 2, h = z & 3;
  const bf16* Qbase = Qb + ((long)(b * SEQ + m0)) * DM + h * HD;
  const bf16* Kbase = Kb + ((long)(b * SEQ)) * DM + h * HD;
  const int rsel = lane & 15, ksel = (lane >> 4) * 8;
  const int rl = (lane >> 4) * 4;

  f32x4 acc[8] = {};

  for (int k0 = 0; k0 < HD; k0 += 32) {
#pragma unroll
    for (int p = 0; p < 8; ++p) {
      int f = (p * 512 + tid) * 8;
      int row = f >> 5, col = f & 31;
      gld_lds16(Kbase + (long)row * DM + k0 + col, &bL[f]);
    }
    bf16x8 af = *(const bf16x8*)(Qbase + (long)rsel * DM + k0 + ksel);
    __syncthreads();
#pragma unroll
    for (int n = 0; n < 8; ++n) {
      bf16x8 bfr = *(const bf16x8*)&bL[(wid * 128 + n * 16 + rsel) * 32 + ksel];
      acc[n] = __builtin_amdgcn_mfma_f32_16x16x32_bf16(af, bfr, acc[n], 0, 0, 0);
    }
    __syncthreads();
  }

  // scale + bias; wave-local row max over this wave's 128 cols
  float* red = (float*)bL;  // [0:128) max partials, [128:256) sum partials
  float bv[8];
#pragma unroll
  for (int n = 0; n < 8; ++n)
    bv[n] = biasarr[(z << 10) + wid * 128 + n * 16 + rsel];

  float pm[4];
#pragma unroll
  for (int j = 0; j < 4; ++j) {
    float mx = -1e30f;
#pragma unroll
    for (int n = 0; n < 8; ++n) {
      acc[n][j] = fmaf(acc[n][j], SCALE, bv[n]);
      mx = fmaxf(mx, acc[n][j]);
    }
    pm[j] = mx;
  }
#pragma unroll
  for (int d = 1; d < 16; d <<= 1)
#pragma unroll
    for (int j = 0; j < 4; ++j) pm[j] = fmaxf(pm[j], __shfl_xor(pm[j], d));
  if (rsel == 0) {
#pragma unroll
    for (int j = 0; j < 4; ++j) red[wid * 16 + rl + j] = pm[j];
  }
  __syncthreads();

  float rmax[4];
#pragma unroll
  for (int j = 0; j < 4; ++j) {
    float mx = red[rl + j];
#pragma unroll
    for (int w = 1; w < 8; ++w) mx = fmaxf(mx, red[w * 16 + rl + j]);
    rmax[j] = mx;
  }

  float ps[4];
#pragma unroll
  for (int j = 0; j < 4; ++j) {
    float s = 0.0f;
#pragma unroll
    for (int n = 0; n < 8; ++n) {
      float e = __expf(acc[n][j] - rmax[j]);
      acc[n][j] = e;
      s += e;
    }
    ps[j] = s;
  }
#pragma unroll
  for (int d = 1; d < 16; d <<= 1)
#pragma unroll
    for (int j = 0; j < 4; ++j) ps[j] += __shfl_xor(ps[j], d);
  if (rsel == 0) {
#pragma unroll
    for (int j = 0; j < 4; ++j) red[128 + wid * 16 + rl + j] = ps[j];
  }
  __syncthreads();

#pragma unroll
  for (int j = 0; j < 4; ++j) {
    float tot = red[128 + rl + j];
#pragma unroll
    for (int w = 1; w < 8; ++w) tot += red[128 + w * 16 + rl + j];
    float inv = 1.0f / tot;
#pragma unroll
    for (int n = 0; n < 8; ++n) acc[n][j] *= inv;
  }
  __syncthreads();  // red region dead before staging reuse

  // staged coalesced write-out: per wave a private 16x128 f32 region (8 KB)
  float* Lf = (float*)bL + wid * 2048;
#pragma unroll
  for (int j = 0; j < 4; ++j)
#pragma unroll
    for (int n = 0; n < 8; ++n)
      Lf[(rl + j) * 128 + n * 16 + rsel] = acc[n][j];
  // per-wave private region: no cross-wave barrier needed
  const long arowbase = ((long)z << 20) + ((long)m0 << 10) + wid * 128;
#pragma unroll
  for (int it = 0; it < 8; ++it) {
    int row = it * 2 + (lane >> 5);
    int col = (lane & 31) * 4;
    f32x4 v = *(const f32x4*)&Lf[row * 128 + col];
    *(f32x4*)&attn[arowbase + ((long)row << 10) + col] = v;
  }
}

// ---------------- GEMM (A row-major [M,K] bf16, BT row-major [N,K] bf16) ----------------
// MODE 0: bf16 out natural +cb1                  (K projection)
// MODE 4: f32 out = acc + cb1 + resid            (final x)
// MODE 5: A f32 batched (attn), out bf16 ctx at col h*HD (PV)
// MODE 6: fused QV: ng<768 -> Q natural (+cb1); else V scatter-transposed (+cb2)
template <int MODE>
__global__ __launch_bounds__(256) void gemm_bt(
    const bf16* __restrict__ A, int lda,
    const bf16* __restrict__ BT, int ldb,
    const float* __restrict__ Af,
    int M, int N, int Kd,
    const float* __restrict__ cb1,
    const float* __restrict__ cb2,
    const float* __restrict__ resid,
    void* __restrict__ out, void* __restrict__ out2) {
  __shared__ __attribute__((aligned(16))) bf16 aL[128 * 32];
  __shared__ __attribute__((aligned(16))) bf16 bL[128 * 32];
  const int tid = threadIdx.x;
  const int lane = tid & 63;
  const int wid = tid >> 6;
  const int wr = wid >> 1, wc = wid & 1;
  int bx, by, bz;
  if constexpr (MODE == 5) {
    int idd = blockIdx.x;
    bz = idd & 31;
    bx = (idd >> 5) & 1;
    by = idd >> 6;
  } else {
    bx = blockIdx.x; by = blockIdx.y; bz = 0;
  }
  const int m0 = by * 128, n0 = bx * 128;

  const bf16* Bb = BT;
  const float* Afb = Af;
  if constexpr (MODE == 5) {
    Bb = BT + (((long)((bz >> 2) * DM + (bz & 3) * HD)) << 10);
    Afb = Af + ((long)bz << 20);
  }

  f32x4 acc[4][4] = {};

  for (int k0 = 0; k0 < Kd; k0 += 32) {
    if constexpr (MODE == 5) {
#pragma unroll
      for (int p = 0; p < 2; ++p) {
        int f = (p * 256 + tid) * 8;
        int row = f >> 5, col = f & 31;
        const float* g = Afb + (long)(m0 + row) * lda + k0 + col;
        f32x4 x0 = *(const f32x4*)g;
        f32x4 x1 = *(const f32x4*)(g + 4);
        bf16x8 t;
        t[0] = (bf16)x0[0]; t[1] = (bf16)x0[1]; t[2] = (bf16)x0[2]; t[3] = (bf16)x0[3];
        t[4] = (bf16)x1[0]; t[5] = (bf16)x1[1]; t[6] = (bf16)x1[2]; t[7] = (bf16)x1[3];
        *(bf16x8*)&aL[f] = t;
      }
    } else {
#pragma unroll
      for (int p = 0; p < 2; ++p) {
        int f = (p * 256 + tid) * 8;
        int row = f >> 5, col = f & 31;
        gld_lds16(A + (long)(m0 + row) * lda + k0 + col, &aL[f]);
      }
    }
#pragma unroll
    for (int p = 0; p < 2; ++p) {
      int f = (p * 256 + tid) * 8;
      int row = f >> 5, col = f & 31;
      int nn = n0 + row;
      nn = nn < N ? nn : N - 1;
      gld_lds16(Bb + (long)nn * ldb + k0 + col, &bL[f]);
    }
    __syncthreads();

    const int rsel = lane & 15, ksel = (lane >> 4) * 8;
    bf16x8 af[4], bfr[4];
#pragma unroll
    for (int m = 0; m < 4; ++m)
      af[m] = *(const bf16x8*)&aL[(wr * 64 + m * 16 + rsel) * 32 + ksel];
#pragma unroll
    for (int n = 0; n < 4; ++n)
      bfr[n] = *(const bf16x8*)&bL[(wc * 64 + n * 16 + rsel) * 32 + ksel];
#pragma unroll
    for (int m = 0; m < 4; ++m)
#pragma unroll
      for (int n = 0; n < 4; ++n)
        acc[m][n] = __builtin_amdgcn_mfma_f32_16x16x32_bf16(af[m], bfr[n], acc[m][n], 0, 0, 0);
    __syncthreads();
  }

  const int rl = (lane >> 4) * 4, cl = lane & 15;
#pragma unroll
  for (int m = 0; m < 4; ++m) {
#pragma unroll
    for (int n = 0; n < 4; ++n) {
      int ng = n0 + wc * 64 + n * 16 + cl;
      if (ng >= N) continue;
#pragma unroll
      for (int j = 0; j < 4; ++j) {
        int mg = m0 + wr * 64 + m * 16 + rl + j;
        float v = acc[m][n][j];
        if constexpr (MODE == 0) {
          ((bf16*)out)[(long)mg * DM + ng] = (bf16)(v + cb1[ng]);
        } else if constexpr (MODE == 5) {
          ((bf16*)out)[(long)((bz >> 2) * SEQ + mg) * DM + (bz & 3) * HD + ng] = (bf16)v;
        } else if constexpr (MODE == 6) {
          if (ng < DM) {
            ((bf16*)out)[(long)mg * DM + ng] = (bf16)(v + cb1[ng]);
          } else {
            int d = ng - DM;
            int b = mg >> 10, s = mg & 1023;
            ((bf16*)out2)[((long)(b * DM + d) << 10) + s] = (bf16)(v + cb2[d]);
          }
        } else {
          long o = (long)mg * DM + ng;
          ((float*)out)[o] = v + cb1[ng] + resid[o];
        }
      }
    }
  }
}

// ---------------- layernorm (one wave per row of 768, in place) ----------------
__global__ __launch_bounds__(256) void layernorm_rows(float* x, const float* __restrict__ gam,
                                                      const float* __restrict__ bet) {
  int row = blockIdx.x * 4 + (threadIdx.x >> 6);
  int lane = threadIdx.x & 63;
  float* r = x + (long)row * DM;
  f32x4 v[3];
#pragma unroll
  for (int i = 0; i < 3; ++i) v[i] = *(const f32x4*)&r[i * 256 + lane * 4];
  float s = 0.0f, ss = 0.0f;
#pragma unroll
  for (int i = 0; i < 3; ++i)
#pragma unroll
    for (int j = 0; j < 4; ++j) {
      s += v[i][j];
      ss += v[i][j] * v[i][j];
    }
  for (int d = 1; d < 64; d <<= 1) {
    s += __shfl_xor(s, d);
    ss += __shfl_xor(ss, d);
  }
  float mu = s * (1.0f / 768.0f);
  float var = ss * (1.0f / 768.0f) - mu * mu;
  float rs = 1.0f / sqrtf(var + 1e-5f);
#pragma unroll
  for (int i = 0; i < 3; ++i) {
#pragma unroll
    for (int j = 0; j < 4; ++j) {
      int c = i * 256 + lane * 4 + j;
      v[i][j] = (v[i][j] - mu) * rs * gam[c] + bet[c];
    }
    *(f32x4*)&r[i * 256 + lane * 4] = v[i];
  }
}

// ---------------- launcher ----------------
extern "C" void kernel_launch(void* const* d_in, const int* in_sizes, int n_in,
                              void* d_out, int out_size, void* d_ws, size_t ws_size,
                              hipStream_t stream) {
  const float* Xd = (const float*)d_in[0];
  const float* Xb = (const float*)d_in[1];
  const float* Wq = (const float*)d_in[2];
  const float* bq = (const float*)d_in[3];
  const float* Wk = (const float*)d_in[4];
  const float* bk = (const float*)d_in[5];
  const float* Wv = (const float*)d_in[6];
  const float* bv = (const float*)d_in[7];
  const float* Wb1 = (const float*)d_in[8];
  const float* bb1 = (const float*)d_in[9];
  const float* Wb2 = (const float*)d_in[10];
  const float* bb2 = (const float*)d_in[11];
  const float* Wo = (const float*)d_in[12];
  const float* bo = (const float*)d_in[13];
  const float* lng = (const float*)d_in[14];
  const float* lnb = (const float*)d_in[15];

  float* y = (float*)d_out;                  // 8192*768 f32
  float* attn = y + (long)MROWS * DM;        // 32*1024*1024 f32

  char* w = (char*)d_ws;
  bf16* Xd_bf = (bf16*)w; w += (long)MROWS * DM * 2;   // later reused as ctx
  bf16* Xb_bf = (bf16*)w; w += (long)MROWS * DB * 2;
  bf16* WqvT = (bf16*)w; w += (long)2 * DM * DM * 2;   // [1536][768]
  bf16* WkT = (bf16*)w; w += (long)DM * DB * 2;
  bf16* WoT = (bf16*)w; w += (long)DM * DM * 2;
  bf16* Qb = (bf16*)w; w += (long)MROWS * DM * 2;
  bf16* Kb = (bf16*)w; w += (long)MROWS * DM * 2;
  bf16* VTb = (bf16*)w; w += (long)MROWS * DM * 2;
  float* biasarr = (float*)w; w += (long)BATCH * NHEADS * SEQ * 4;
  bf16* ctxb = Xd_bf;  // Xd_bf dead after QV projection; reuse for ctx

  dim3 blk(256);
  cvt_f32_bf16<<<6144, blk, 0, stream>>>(Xd, Xd_bf, (long)MROWS * DM / 4);
  cvt_f32_bf16<<<512, blk, 0, stream>>>(Xb, Xb_bf, (long)MROWS * DB / 4);
  prep_weights<<<7104, blk, 0, stream>>>(Wq, Wv, Wk, Wo,
                                         WqvT, WqvT + (long)DM * DM, WkT, WoT);
  bias_mlp<<<32, blk, 0, stream>>>(Xb, Wb1, bb1, Wb2, bb2, biasarr);

  // K = Xb @ Wk + bk
  gemm_bt<0><<<dim3(6, 64, 1), blk, 0, stream>>>(Xb_bf, DB, WkT, DB, nullptr, MROWS, DM, DB,
                                                 bk, nullptr, nullptr, Kb, nullptr);
  // [Q | V] = Xd @ [Wq | Wv]: Q natural -> Qb, V scatter-transposed -> VTb
  gemm_bt<6><<<dim3(12, 64, 1), blk, 0, stream>>>(Xd_bf, DM, WqvT, DM, nullptr, MROWS, 2 * DM, DM,
                                                  bq, bv, nullptr, Qb, VTb);
  // scores + bias + softmax fused -> attn f32 (16-row blocks, 2 blocks/CU)
  scores_softmax<<<2048, 512, 0, stream>>>(Qb, Kb, biasarr, attn);
  // ctx = attn @ V  (reads f32 attn, converts during staging)
  gemm_bt<5><<<512, blk, 0, stream>>>(nullptr, SEQ, VTb, SEQ, attn, SEQ, HD, SEQ,
                                      nullptr, nullptr, nullptr, ctxb, nullptr);
  // x = ctx @ Wo + bo + resid -> y region, then LN in place
  gemm_bt<4><<<dim3(6, 64, 1), blk, 0, stream>>>(ctxb, DM, WoT, DM, nullptr, MROWS, DM, DM,
                                                 bo, nullptr, Xd, y, nullptr);
  layernorm_rows<<<2048, 256, 0, stream>>>(y, lng, lnb);
}

// Round 11
// 234.031 us; speedup vs baseline: 1.0673x; 1.0465x over previous
//
#include <hip/hip_runtime.h>
#include <hip/hip_bf16.h>
#include <math.h>
#include <stdint.h>

typedef __bf16 bf16;
typedef __bf16 bf16x8 __attribute__((ext_vector_type(8)));
typedef __bf16 bf16x4v __attribute__((ext_vector_type(4)));
typedef float f32x4 __attribute__((ext_vector_type(4)));

#define NHEADS 4
#define DM 768
#define DB 64
#define HD 192
#define BATCH 8
#define SEQ 1024
#define MROWS 8192
#define SCALE 0.07216878364870323f

__device__ __forceinline__ void gld_lds16(const void* g, void* l) {
  __builtin_amdgcn_global_load_lds(
      (__attribute__((address_space(1))) void*)(void*)g,
      (__attribute__((address_space(3))) void*)l, 16, 0, 0);
}

// ---------------- converts ----------------
__global__ __launch_bounds__(256) void cvt_f32_bf16(const float* __restrict__ in,
                                                    bf16* __restrict__ out, long n4) {
  long i = (long)blockIdx.x * blockDim.x + threadIdx.x;
  if (i >= n4) return;
  f32x4 v = *(const f32x4*)&in[i * 4];
  bf16x4v t;
  t[0] = (bf16)v[0]; t[1] = (bf16)v[1]; t[2] = (bf16)v[2]; t[3] = (bf16)v[3];
  *(bf16x4v*)&out[i * 4] = t;
}

// ---------------- fused weight prep: 4 transposes in one launch ----------------
__global__ __launch_bounds__(256) void prep_weights(
    const float* __restrict__ Wq, const float* __restrict__ Wv,
    const float* __restrict__ Wk, const float* __restrict__ Wo,
    bf16* __restrict__ WT0, bf16* __restrict__ WT1,
    bf16* __restrict__ WT2, bf16* __restrict__ WT3) {
  int id = blockIdx.x;
  const float* W;
  bf16* WT;
  int K, base;
  if (id < 2304)      { W = Wq; WT = WT0; K = DM; base = 0; }
  else if (id < 4608) { W = Wv; WT = WT1; K = DM; base = 2304; }
  else if (id < 4800) { W = Wk; WT = WT2; K = DB; base = 4608; }
  else                { W = Wo; WT = WT3; K = DM; base = 4800; }
  long idx = (long)(id - base) * 256 + threadIdx.x;
  if (idx >= (long)K * DM) return;
  int k = (int)(idx % K);
  int n = (int)(idx / K);
  WT[(long)n * K + k] = (bf16)W[(long)k * DM + n];
}

// ---------------- bias MLP ----------------
__global__ __launch_bounds__(256) void bias_mlp(const float* __restrict__ bloom,
                                                const float* __restrict__ Wb1,
                                                const float* __restrict__ bb1,
                                                const float* __restrict__ Wb2,
                                                const float* __restrict__ bb2,
                                                float* __restrict__ biasarr) {
  int idx = blockIdx.x * blockDim.x + threadIdx.x;
  if (idx >= MROWS) return;
  const float* x = bloom + (long)idx * DB;
  float h[8];
#pragma unroll
  for (int j = 0; j < 8; ++j) h[j] = bb1[j];
  for (int k = 0; k < DB; ++k) {
    float xv = x[k];
#pragma unroll
    for (int j = 0; j < 8; ++j) h[j] = fmaf(xv, Wb1[k * 8 + j], h[j]);
  }
#pragma unroll
  for (int j = 0; j < 8; ++j) {
    float a = h[j];
    h[j] = 0.5f * a * (1.0f + erff(a * 0.7071067811865476f));
  }
  int b = idx >> 10, s = idx & 1023;
#pragma unroll
  for (int o = 0; o < 4; ++o) {
    float a = bb2[o];
#pragma unroll
    for (int j = 0; j < 8; ++j) a = fmaf(h[j], Wb2[j * 4 + o], a);
    biasarr[((long)(b * 4 + o) << 10) + s] = a;
  }
}

// ---------------- inv from partials ----------------
// 128 blocks x 256: row r sums partials[r][0..15] -> inv[r] = 1/sum
__global__ __launch_bounds__(256) void make_inv(const float* __restrict__ part,
                                                float* __restrict__ inv) {
  int r = blockIdx.x * 256 + threadIdx.x;
  const float* p = part + (long)r * 16;
  float s = 0.0f;
#pragma unroll
  for (int i = 0; i < 4; ++i) {
    f32x4 v = *(const f32x4*)&p[i * 4];
    s += v[0] + v[1] + v[2] + v[3];
  }
  inv[r] = 1.0f / s;
}

// fallback: E was written f32 into attn; normalize in place.
__global__ __launch_bounds__(256) void rowsum_scale_f32(float* __restrict__ attn) {
  const int row = blockIdx.x * 4 + (threadIdx.x >> 6);
  const int lane = threadIdx.x & 63;
  float* ar = attn + ((long)row << 10);
  f32x4 v[4];
#pragma unroll
  for (int i = 0; i < 4; ++i) v[i] = *(const f32x4*)&ar[i * 256 + lane * 4];
  float s = 0.0f;
#pragma unroll
  for (int i = 0; i < 4; ++i)
#pragma unroll
    for (int j = 0; j < 4; ++j) s += v[i][j];
  for (int d = 1; d < 64; d <<= 1) s += __shfl_xor(s, d);
  float iv = 1.0f / s;
#pragma unroll
  for (int i = 0; i < 4; ++i) {
#pragma unroll
    for (int j = 0; j < 4; ++j) v[i][j] *= iv;
    *(f32x4*)&ar[i * 256 + lane * 4] = v[i];
  }
}

// ---------------- GEMM (A row-major [M,K] bf16, BT row-major [N,K] bf16) ----------------
// MODE 0: bf16 out natural +cb1                               (K projection)
// MODE 2: E = exp(v*SCALE+bias) bf16 + row-partials -> out2   (scores, 2048 blocks)
// MODE 7: like 2 but f32 out into attn, no partials           (fallback)
// MODE 8: A=E bf16 batched, staged *inv(cb2); bx==0 writes f32 attn (out2); ctx out
// MODE 5: A f32 batched (normalized attn), out bf16 ctx       (PV fallback)
// MODE 4: f32 out = acc + cb1 + resid                         (final x)
// MODE 6: fused QV: ng<768 -> Q natural (+cb1); else V scatter-transposed (+cb2)
template <int MODE>
__global__ __launch_bounds__(256) void gemm_bt(
    const bf16* __restrict__ A, int lda,
    const bf16* __restrict__ BT, int ldb,
    const float* __restrict__ Af,
    int M, int N, int Kd,
    const float* __restrict__ cb1,
    const float* __restrict__ cb2,
    const float* __restrict__ resid,
    void* __restrict__ out, void* __restrict__ out2) {
  __shared__ __attribute__((aligned(16))) bf16 aL[128 * 32];
  __shared__ __attribute__((aligned(16))) bf16 bL[128 * 32];
  const int tid = threadIdx.x;
  const int lane = tid & 63;
  const int wid = tid >> 6;
  const int wr = wid >> 1, wc = wid & 1;
  int bx, by, bz;
  if constexpr (MODE == 2 || MODE == 7) {
    int idd = blockIdx.x;
    bz = idd & 31;
    int t = idd >> 5;
    bx = t & 7;
    by = t >> 3;
  } else if constexpr (MODE == 5 || MODE == 8) {
    int idd = blockIdx.x;
    bz = idd & 31;
    bx = (idd >> 5) & 1;
    by = idd >> 6;
  } else {
    bx = blockIdx.x; by = blockIdx.y; bz = 0;
  }
  const int m0 = by * 128, n0 = bx * 128;

  const bf16* Ab = A;
  const bf16* Bb = BT;
  const float* Afb = Af;
  if constexpr (MODE == 2 || MODE == 7) {
    long o = ((long)((bz >> 2) * SEQ)) * DM + (long)(bz & 3) * HD;
    Ab = A + o;
    Bb = BT + o;
  }
  if constexpr (MODE == 8) {
    Ab = A + ((long)bz << 20);
    Bb = BT + (((long)((bz >> 2) * DM + (bz & 3) * HD)) << 10);
  }
  if constexpr (MODE == 5) {
    Bb = BT + (((long)((bz >> 2) * DM + (bz & 3) * HD)) << 10);
    Afb = Af + ((long)bz << 20);
  }
  const bool writeAttn = (MODE == 8) && (bx == 0);

  f32x4 acc[4][4] = {};

  for (int k0 = 0; k0 < Kd; k0 += 32) {
    if constexpr (MODE == 5) {
#pragma unroll
      for (int p = 0; p < 2; ++p) {
        int f = (p * 256 + tid) * 8;
        int row = f >> 5, col = f & 31;
        const float* g = Afb + (long)(m0 + row) * lda + k0 + col;
        f32x4 x0 = *(const f32x4*)g;
        f32x4 x1 = *(const f32x4*)(g + 4);
        bf16x8 t;
        t[0] = (bf16)x0[0]; t[1] = (bf16)x0[1]; t[2] = (bf16)x0[2]; t[3] = (bf16)x0[3];
        t[4] = (bf16)x1[0]; t[5] = (bf16)x1[1]; t[6] = (bf16)x1[2]; t[7] = (bf16)x1[3];
        *(bf16x8*)&aL[f] = t;
      }
    } else if constexpr (MODE == 8) {
#pragma unroll
      for (int p = 0; p < 2; ++p) {
        int f = (p * 256 + tid) * 8;
        int row = f >> 5, col = f & 31;
        bf16x8 e = *(const bf16x8*)(Ab + (long)(m0 + row) * lda + k0 + col);
        float iv = cb2[(bz << 10) + m0 + row];
        float fv[8];
#pragma unroll
        for (int q = 0; q < 8; ++q) fv[q] = (float)e[q] * iv;
        if (writeAttn) {
          float* ap = (float*)out2 + ((long)bz << 20) + ((long)(m0 + row) << 10) + k0 + col;
          f32x4 w0, w1;
          w0[0] = fv[0]; w0[1] = fv[1]; w0[2] = fv[2]; w0[3] = fv[3];
          w1[0] = fv[4]; w1[1] = fv[5]; w1[2] = fv[6]; w1[3] = fv[7];
          *(f32x4*)ap = w0;
          *(f32x4*)(ap + 4) = w1;
        }
        bf16x8 t;
#pragma unroll
        for (int q = 0; q < 8; ++q) t[q] = (bf16)fv[q];
        *(bf16x8*)&aL[f] = t;
      }
    } else {
#pragma unroll
      for (int p = 0; p < 2; ++p) {
        int f = (p * 256 + tid) * 8;
        int row = f >> 5, col = f & 31;
        gld_lds16(Ab + (long)(m0 + row) * lda + k0 + col, &aL[f]);
      }
    }
#pragma unroll
    for (int p = 0; p < 2; ++p) {
      int f = (p * 256 + tid) * 8;
      int row = f >> 5, col = f & 31;
      int nn = n0 + row;
      nn = nn < N ? nn : N - 1;
      gld_lds16(Bb + (long)nn * ldb + k0 + col, &bL[f]);
    }
    __syncthreads();

    const int rsel = lane & 15, ksel = (lane >> 4) * 8;
    bf16x8 af[4], bfr[4];
#pragma unroll
    for (int m = 0; m < 4; ++m)
      af[m] = *(const bf16x8*)&aL[(wr * 64 + m * 16 + rsel) * 32 + ksel];
#pragma unroll
    for (int n = 0; n < 4; ++n)
      bfr[n] = *(const bf16x8*)&bL[(wc * 64 + n * 16 + rsel) * 32 + ksel];
#pragma unroll
    for (int m = 0; m < 4; ++m)
#pragma unroll
      for (int n = 0; n < 4; ++n)
        acc[m][n] = __builtin_amdgcn_mfma_f32_16x16x32_bf16(af[m], bfr[n], acc[m][n], 0, 0, 0);
    __syncthreads();
  }

  const int rl = (lane >> 4) * 4, cl = lane & 15;

  if constexpr (MODE == 2) {
    // transform acc -> E = exp(scale*v + bias[col]) in place
    float bvv[4];
#pragma unroll
    for (int n = 0; n < 4; ++n)
      bvv[n] = cb2[(bz << 10) + n0 + wc * 64 + n * 16 + cl];
#pragma unroll
    for (int m = 0; m < 4; ++m)
#pragma unroll
      for (int n = 0; n < 4; ++n)
#pragma unroll
        for (int j = 0; j < 4; ++j)
          acc[m][n][j] = __expf(fmaf(acc[m][n][j], SCALE, bvv[n]));
    // row-partial sums over this block's 128 cols -> out2[row][bx*2+wc]
    float* part = (float*)out2;
#pragma unroll
    for (int m = 0; m < 4; ++m) {
#pragma unroll
      for (int j = 0; j < 4; ++j) {
        float s = acc[m][0][j] + acc[m][1][j] + acc[m][2][j] + acc[m][3][j];
#pragma unroll
        for (int d = 1; d < 16; d <<= 1) s += __shfl_xor(s, d);
        if (cl == 0) {
          int mg = m0 + wr * 64 + m * 16 + rl + j;
          part[((((long)bz << 10) + mg) << 4) + bx * 2 + wc] = s;
        }
      }
    }
  }

#pragma unroll
  for (int m = 0; m < 4; ++m) {
#pragma unroll
    for (int n = 0; n < 4; ++n) {
      int ng = n0 + wc * 64 + n * 16 + cl;
      if (ng >= N) continue;
#pragma unroll
      for (int j = 0; j < 4; ++j) {
        int mg = m0 + wr * 64 + m * 16 + rl + j;
        float v = acc[m][n][j];
        if constexpr (MODE == 0) {
          ((bf16*)out)[(long)mg * DM + ng] = (bf16)(v + cb1[ng]);
        } else if constexpr (MODE == 2) {
          ((bf16*)out)[((long)bz << 20) + ((long)mg << 10) + ng] = (bf16)v;
        } else if constexpr (MODE == 7) {
          ((float*)out)[((long)bz << 20) + ((long)mg << 10) + ng] =
              __expf(fmaf(v, SCALE, cb2[(bz << 10) + ng]));
        } else if constexpr (MODE == 5 || MODE == 8) {
          ((bf16*)out)[(long)((bz >> 2) * SEQ + mg) * DM + (bz & 3) * HD + ng] = (bf16)v;
        } else if constexpr (MODE == 6) {
          if (ng < DM) {
            ((bf16*)out)[(long)mg * DM + ng] = (bf16)(v + cb1[ng]);
          } else {
            int d = ng - DM;
            int b = mg >> 10, s = mg & 1023;
            ((bf16*)out2)[((long)(b * DM + d) << 10) + s] = (bf16)(v + cb2[d]);
          }
        } else {
          long o = (long)mg * DM + ng;
          ((float*)out)[o] = v + cb1[ng] + resid[o];
        }
      }
    }
  }
}

// ---------------- layernorm (one wave per row of 768, in place) ----------------
__global__ __launch_bounds__(256) void layernorm_rows(float* x, const float* __restrict__ gam,
                                                      const float* __restrict__ bet) {
  int row = blockIdx.x * 4 + (threadIdx.x >> 6);
  int lane = threadIdx.x & 63;
  float* r = x + (long)row * DM;
  f32x4 v[3];
#pragma unroll
  for (int i = 0; i < 3; ++i) v[i] = *(const f32x4*)&r[i * 256 + lane * 4];
  float s = 0.0f, ss = 0.0f;
#pragma unroll
  for (int i = 0; i < 3; ++i)
#pragma unroll
    for (int j = 0; j < 4; ++j) {
      s += v[i][j];
      ss += v[i][j] * v[i][j];
    }
  for (int d = 1; d < 64; d <<= 1) {
    s += __shfl_xor(s, d);
    ss += __shfl_xor(ss, d);
  }
  float mu = s * (1.0f / 768.0f);
  float var = ss * (1.0f / 768.0f) - mu * mu;
  float rs = 1.0f / sqrtf(var + 1e-5f);
#pragma unroll
  for (int i = 0; i < 3; ++i) {
#pragma unroll
    for (int j = 0; j < 4; ++j) {
      int c = i * 256 + lane * 4 + j;
      v[i][j] = (v[i][j] - mu) * rs * gam[c] + bet[c];
    }
    *(f32x4*)&r[i * 256 + lane * 4] = v[i];
  }
}

// ---------------- launcher ----------------
extern "C" void kernel_launch(void* const* d_in, const int* in_sizes, int n_in,
                              void* d_out, int out_size, void* d_ws, size_t ws_size,
                              hipStream_t stream) {
  const float* Xd = (const float*)d_in[0];
  const float* Xb = (const float*)d_in[1];
  const float* Wq = (const float*)d_in[2];
  const float* bq = (const float*)d_in[3];
  const float* Wk = (const float*)d_in[4];
  const float* bk = (const float*)d_in[5];
  const float* Wv = (const float*)d_in[6];
  const float* bv = (const float*)d_in[7];
  const float* Wb1 = (const float*)d_in[8];
  const float* bb1 = (const float*)d_in[9];
  const float* Wb2 = (const float*)d_in[10];
  const float* bb2 = (const float*)d_in[11];
  const float* Wo = (const float*)d_in[12];
  const float* bo = (const float*)d_in[13];
  const float* lng = (const float*)d_in[14];
  const float* lnb = (const float*)d_in[15];

  float* y = (float*)d_out;                  // 8192*768 f32
  float* attn = y + (long)MROWS * DM;        // 32*1024*1024 f32

  char* w = (char*)d_ws;
  bf16* Xd_bf = (bf16*)w; w += (long)MROWS * DM * 2;   // later reused as ctx
  bf16* Xb_bf = (bf16*)w; w += (long)MROWS * DB * 2;
  bf16* WqvT = (bf16*)w; w += (long)2 * DM * DM * 2;   // [1536][768]
  bf16* WkT = (bf16*)w; w += (long)DM * DB * 2;
  bf16* WoT = (bf16*)w; w += (long)DM * DM * 2;
  bf16* Qb = (bf16*)w; w += (long)MROWS * DM * 2;
  bf16* Kb = (bf16*)w; w += (long)MROWS * DM * 2;
  bf16* VTb = (bf16*)w; w += (long)MROWS * DM * 2;
  float* biasarr = (float*)w; w += (long)BATCH * NHEADS * SEQ * 4;
  float* part = (float*)w; w += (long)32 * SEQ * 16 * 4;   // 2 MB partials
  float* inv = (float*)w; w += (long)32 * SEQ * 4;         // 128 KB
  bf16* Sb = (bf16*)w; w += (long)32 * SEQ * SEQ * 2;      // 64 MB E buffer
  const bool useS = ((size_t)(w - (char*)d_ws)) <= ws_size;
  bf16* ctxb = Xd_bf;  // Xd_bf dead after QV projection; reuse for ctx

  dim3 blk(256);
  cvt_f32_bf16<<<6144, blk, 0, stream>>>(Xd, Xd_bf, (long)MROWS * DM / 4);
  cvt_f32_bf16<<<512, blk, 0, stream>>>(Xb, Xb_bf, (long)MROWS * DB / 4);
  prep_weights<<<7104, blk, 0, stream>>>(Wq, Wv, Wk, Wo,
                                         WqvT, WqvT + (long)DM * DM, WkT, WoT);
  bias_mlp<<<32, blk, 0, stream>>>(Xb, Wb1, bb1, Wb2, bb2, biasarr);

  // K = Xb @ Wk + bk
  gemm_bt<0><<<dim3(6, 64, 1), blk, 0, stream>>>(Xb_bf, DB, WkT, DB, nullptr, MROWS, DM, DB,
                                                 bk, nullptr, nullptr, Kb, nullptr);
  // [Q | V] = Xd @ [Wq | Wv]: Q natural -> Qb, V scatter-transposed -> VTb
  gemm_bt<6><<<dim3(12, 64, 1), blk, 0, stream>>>(Xd_bf, DM, WqvT, DM, nullptr, MROWS, 2 * DM, DM,
                                                  bq, bv, nullptr, Qb, VTb);
  if (useS) {
    // E = exp(QK^T*scale + bias) bf16 + row-partials
    gemm_bt<2><<<2048, blk, 0, stream>>>(Qb, DM, Kb, DM, nullptr, SEQ, SEQ, HD,
                                         nullptr, biasarr, nullptr, Sb, part);
    make_inv<<<128, blk, 0, stream>>>(part, inv);
    // PV: stage E*inv (writes f32 attn from bx==0), MFMA -> ctx
    gemm_bt<8><<<512, blk, 0, stream>>>(Sb, SEQ, VTb, SEQ, nullptr, SEQ, HD, SEQ,
                                        nullptr, inv, nullptr, ctxb, attn);
  } else {
    gemm_bt<7><<<2048, blk, 0, stream>>>(Qb, DM, Kb, DM, nullptr, SEQ, SEQ, HD,
                                         nullptr, biasarr, nullptr, attn, nullptr);
    rowsum_scale_f32<<<8192, blk, 0, stream>>>(attn);
    gemm_bt<5><<<512, blk, 0, stream>>>(nullptr, SEQ, VTb, SEQ, attn, SEQ, HD, SEQ,
                                        nullptr, nullptr, nullptr, ctxb, nullptr);
  }
  // x = ctx @ Wo + bo + resid -> y region, then LN in place
  gemm_bt<4><<<dim3(6, 64, 1), blk, 0, stream>>>(ctxb, DM, WoT, DM, nullptr, MROWS, DM, DM,
                                                 bo, nullptr, Xd, y, nullptr);
  layernorm_rows<<<2048, 256, 0, stream>>>(y, lng, lnb);
}

// Round 12
// 216.631 us; speedup vs baseline: 1.1530x; 1.0803x over previous
//
#include <hip/hip_runtime.h>
#include <hip/hip_bf16.h>
#include <math.h>
#include <stdint.h>

typedef __bf16 bf16;
typedef __bf16 bf16x8 __attribute__((ext_vector_type(8)));
typedef __bf16 bf16x4v __attribute__((ext_vector_type(4)));
typedef float f32x4 __attribute__((ext_vector_type(4)));

#define NHEADS 4
#define DM 768
#define DB 64
#define HD 192
#define BATCH 8
#define SEQ 1024
#define MROWS 8192
#define SCALE 0.07216878364870323f

__device__ __forceinline__ void gld_lds16(const void* g, void* l) {
  __builtin_amdgcn_global_load_lds(
      (__attribute__((address_space(1))) void*)(void*)g,
      (__attribute__((address_space(3))) void*)l, 16, 0, 0);
}

// ---------------- fused prologue: cvt Xd, cvt Xb, bias MLP, 4 weight transposes ----------------
// blocks: [0,6144) cvt Xd ; [6144,6656) cvt Xb ; [6656,6688) bias_mlp ; [6688,13792) weights
__global__ __launch_bounds__(256) void prologue(
    const float* __restrict__ Xd, bf16* __restrict__ Xd_bf,
    const float* __restrict__ Xb, bf16* __restrict__ Xb_bf,
    const float* __restrict__ Wq, const float* __restrict__ Wv,
    const float* __restrict__ Wk, const float* __restrict__ Wo,
    bf16* __restrict__ WT0, bf16* __restrict__ WT1,
    bf16* __restrict__ WT2, bf16* __restrict__ WT3,
    const float* __restrict__ Wb1, const float* __restrict__ bb1,
    const float* __restrict__ Wb2, const float* __restrict__ bb2,
    float* __restrict__ biasarr) {
  const int id = blockIdx.x;
  const int tid = threadIdx.x;
  if (id < 6656) {
    const float* in = (id < 6144) ? Xd : Xb;
    bf16* out = (id < 6144) ? Xd_bf : Xb_bf;
    long i = (long)(id < 6144 ? id : id - 6144) * 256 + tid;
    f32x4 v = *(const f32x4*)&in[i * 4];
    bf16x4v t;
    t[0] = (bf16)v[0]; t[1] = (bf16)v[1]; t[2] = (bf16)v[2]; t[3] = (bf16)v[3];
    *(bf16x4v*)&out[i * 4] = t;
  } else if (id < 6688) {
    int idx = (id - 6656) * 256 + tid;
    const float* x = Xb + (long)idx * DB;
    float h[8];
#pragma unroll
    for (int j = 0; j < 8; ++j) h[j] = bb1[j];
    for (int k = 0; k < DB; ++k) {
      float xv = x[k];
#pragma unroll
      for (int j = 0; j < 8; ++j) h[j] = fmaf(xv, Wb1[k * 8 + j], h[j]);
    }
#pragma unroll
    for (int j = 0; j < 8; ++j) {
      float a = h[j];
      h[j] = 0.5f * a * (1.0f + erff(a * 0.7071067811865476f));
    }
    int b = idx >> 10, s = idx & 1023;
#pragma unroll
    for (int o = 0; o < 4; ++o) {
      float a = bb2[o];
#pragma unroll
      for (int j = 0; j < 8; ++j) a = fmaf(h[j], Wb2[j * 4 + o], a);
      biasarr[((long)(b * 4 + o) << 10) + s] = a;
    }
  } else {
    int wi = id - 6688;
    const float* W;
    bf16* WT;
    int K, base;
    if (wi < 2304)      { W = Wq; WT = WT0; K = DM; base = 0; }
    else if (wi < 4608) { W = Wv; WT = WT1; K = DM; base = 2304; }
    else if (wi < 4800) { W = Wk; WT = WT2; K = DB; base = 4608; }
    else                { W = Wo; WT = WT3; K = DM; base = 4800; }
    long idx = (long)(wi - base) * 256 + tid;
    if (idx >= (long)K * DM) return;
    int k = (int)(idx % K);
    int n = (int)(idx / K);
    WT[(long)n * K + k] = (bf16)W[(long)k * DM + n];
  }
}

// ---------------- inv from partials ----------------
__global__ __launch_bounds__(256) void make_inv(const float* __restrict__ part,
                                                float* __restrict__ inv) {
  int r = blockIdx.x * 256 + threadIdx.x;
  const float* p = part + (long)r * 16;
  float s = 0.0f;
#pragma unroll
  for (int i = 0; i < 4; ++i) {
    f32x4 v = *(const f32x4*)&p[i * 4];
    s += v[0] + v[1] + v[2] + v[3];
  }
  inv[r] = 1.0f / s;
}

// fallback: E was written f32 into attn; normalize in place.
__global__ __launch_bounds__(256) void rowsum_scale_f32(float* __restrict__ attn) {
  const int row = blockIdx.x * 4 + (threadIdx.x >> 6);
  const int lane = threadIdx.x & 63;
  float* ar = attn + ((long)row << 10);
  f32x4 v[4];
#pragma unroll
  for (int i = 0; i < 4; ++i) v[i] = *(const f32x4*)&ar[i * 256 + lane * 4];
  float s = 0.0f;
#pragma unroll
  for (int i = 0; i < 4; ++i)
#pragma unroll
    for (int j = 0; j < 4; ++j) s += v[i][j];
  for (int d = 1; d < 64; d <<= 1) s += __shfl_xor(s, d);
  float iv = 1.0f / s;
#pragma unroll
  for (int i = 0; i < 4; ++i) {
#pragma unroll
    for (int j = 0; j < 4; ++j) v[i][j] *= iv;
    *(f32x4*)&ar[i * 256 + lane * 4] = v[i];
  }
}

// ---------------- GEMM (A row-major [M,K] bf16, BT row-major [N,K] bf16) ----------------
// MODE 0: bf16 out natural +cb1                               (K projection)
// MODE 2: E = exp(v*SCALE+bias) bf16 + row-partials -> out2   (scores, 2048 blocks)
// MODE 7: like 2 but f32 out into attn, no partials           (fallback)
// MODE 8: A=E bf16 batched via gld_lds; ctx*inv epilogue; attn f32 written from LDS,
//         k-range split by bx (bx0: k<512, bx1: k>=512), nontemporal    (PV)
// MODE 5: A f32 batched (normalized attn), out bf16 ctx       (PV fallback)
// MODE 4: f32 out = acc + cb1 + resid                         (final x)
// MODE 6: fused QV: ng<768 -> Q natural (+cb1); else V scatter-transposed (+cb2)
template <int MODE>
__global__ __launch_bounds__(256) void gemm_bt(
    const bf16* __restrict__ A, int lda,
    const bf16* __restrict__ BT, int ldb,
    const float* __restrict__ Af,
    int M, int N, int Kd,
    const float* __restrict__ cb1,
    const float* __restrict__ cb2,
    const float* __restrict__ resid,
    void* __restrict__ out, void* __restrict__ out2) {
  __shared__ __attribute__((aligned(16))) bf16 aL[128 * 32];
  __shared__ __attribute__((aligned(16))) bf16 bL[128 * 32];
  const int tid = threadIdx.x;
  const int lane = tid & 63;
  const int wid = tid >> 6;
  const int wr = wid >> 1, wc = wid & 1;
  int bx, by, bz;
  if constexpr (MODE == 2 || MODE == 7) {
    int idd = blockIdx.x;
    bz = idd & 31;
    int t = idd >> 5;
    bx = t & 7;
    by = t >> 3;
  } else if constexpr (MODE == 5 || MODE == 8) {
    int idd = blockIdx.x;
    bz = idd & 31;
    bx = (idd >> 5) & 1;
    by = idd >> 6;
  } else {
    bx = blockIdx.x; by = blockIdx.y; bz = 0;
  }
  const int m0 = by * 128, n0 = bx * 128;

  const bf16* Ab = A;
  const bf16* Bb = BT;
  const float* Afb = Af;
  if constexpr (MODE == 2 || MODE == 7) {
    long o = ((long)((bz >> 2) * SEQ)) * DM + (long)(bz & 3) * HD;
    Ab = A + o;
    Bb = BT + o;
  }
  if constexpr (MODE == 8) {
    Ab = A + ((long)bz << 20);
    Bb = BT + (((long)((bz >> 2) * DM + (bz & 3) * HD)) << 10);
  }
  if constexpr (MODE == 5) {
    Bb = BT + (((long)((bz >> 2) * DM + (bz & 3) * HD)) << 10);
    Afb = Af + ((long)bz << 20);
  }

  // MODE 8: hoist inv for this thread's 2 staged rows (rows fixed across k-steps)
  float iv0 = 0.f, iv1 = 0.f;
  if constexpr (MODE == 8) {
    int r0 = tid >> 2, r1 = 64 + (tid >> 2);
    iv0 = cb2[(bz << 10) + m0 + r0];
    iv1 = cb2[(bz << 10) + m0 + r1];
  }

  f32x4 acc[4][4] = {};

  for (int k0 = 0; k0 < Kd; k0 += 32) {
    if constexpr (MODE == 5) {
#pragma unroll
      for (int p = 0; p < 2; ++p) {
        int f = (p * 256 + tid) * 8;
        int row = f >> 5, col = f & 31;
        const float* g = Afb + (long)(m0 + row) * lda + k0 + col;
        f32x4 x0 = *(const f32x4*)g;
        f32x4 x1 = *(const f32x4*)(g + 4);
        bf16x8 t;
        t[0] = (bf16)x0[0]; t[1] = (bf16)x0[1]; t[2] = (bf16)x0[2]; t[3] = (bf16)x0[3];
        t[4] = (bf16)x1[0]; t[5] = (bf16)x1[1]; t[6] = (bf16)x1[2]; t[7] = (bf16)x1[3];
        *(bf16x8*)&aL[f] = t;
      }
    } else {
#pragma unroll
      for (int p = 0; p < 2; ++p) {
        int f = (p * 256 + tid) * 8;
        int row = f >> 5, col = f & 31;
        gld_lds16(Ab + (long)(m0 + row) * lda + k0 + col, &aL[f]);
      }
    }
#pragma unroll
    for (int p = 0; p < 2; ++p) {
      int f = (p * 256 + tid) * 8;
      int row = f >> 5, col = f & 31;
      int nn = n0 + row;
      nn = nn < N ? nn : N - 1;
      gld_lds16(Bb + (long)nn * ldb + k0 + col, &bL[f]);
    }
    __syncthreads();

    // MODE 8: write this k-slice of normalized attn from LDS (split by bx)
    if constexpr (MODE == 8) {
      if ((k0 < 512) == (bx == 0)) {
#pragma unroll
        for (int p = 0; p < 2; ++p) {
          int f = (p * 256 + tid) * 8;
          int row = f >> 5, col = f & 31;
          bf16x8 e = *(const bf16x8*)&aL[f];
          float iv = p ? iv1 : iv0;
          f32x4 w0, w1;
          w0[0] = (float)e[0] * iv; w0[1] = (float)e[1] * iv;
          w0[2] = (float)e[2] * iv; w0[3] = (float)e[3] * iv;
          w1[0] = (float)e[4] * iv; w1[1] = (float)e[5] * iv;
          w1[2] = (float)e[6] * iv; w1[3] = (float)e[7] * iv;
          float* ap = (float*)out2 + ((long)bz << 20) + ((long)(m0 + row) << 10) + k0 + col;
          __builtin_nontemporal_store(w0, (f32x4*)ap);
          __builtin_nontemporal_store(w1, (f32x4*)(ap + 4));
        }
      }
    }

    const int rsel = lane & 15, ksel = (lane >> 4) * 8;
    bf16x8 af[4], bfr[4];
#pragma unroll
    for (int m = 0; m < 4; ++m)
      af[m] = *(const bf16x8*)&aL[(wr * 64 + m * 16 + rsel) * 32 + ksel];
#pragma unroll
    for (int n = 0; n < 4; ++n)
      bfr[n] = *(const bf16x8*)&bL[(wc * 64 + n * 16 + rsel) * 32 + ksel];
#pragma unroll
    for (int m = 0; m < 4; ++m)
#pragma unroll
      for (int n = 0; n < 4; ++n)
        acc[m][n] = __builtin_amdgcn_mfma_f32_16x16x32_bf16(af[m], bfr[n], acc[m][n], 0, 0, 0);
    __syncthreads();
  }

  const int rl = (lane >> 4) * 4, cl = lane & 15;

  if constexpr (MODE == 2) {
    float bvv[4];
#pragma unroll
    for (int n = 0; n < 4; ++n)
      bvv[n] = cb2[(bz << 10) + n0 + wc * 64 + n * 16 + cl];
#pragma unroll
    for (int m = 0; m < 4; ++m)
#pragma unroll
      for (int n = 0; n < 4; ++n)
#pragma unroll
        for (int j = 0; j < 4; ++j)
          acc[m][n][j] = __expf(fmaf(acc[m][n][j], SCALE, bvv[n]));
    float* part = (float*)out2;
#pragma unroll
    for (int m = 0; m < 4; ++m) {
#pragma unroll
      for (int j = 0; j < 4; ++j) {
        float s = acc[m][0][j] + acc[m][1][j] + acc[m][2][j] + acc[m][3][j];
#pragma unroll
        for (int d = 1; d < 16; d <<= 1) s += __shfl_xor(s, d);
        if (cl == 0) {
          int mg = m0 + wr * 64 + m * 16 + rl + j;
          part[((((long)bz << 10) + mg) << 4) + bx * 2 + wc] = s;
        }
      }
    }
  }

#pragma unroll
  for (int m = 0; m < 4; ++m) {
#pragma unroll
    for (int n = 0; n < 4; ++n) {
      int ng = n0 + wc * 64 + n * 16 + cl;
      if (ng >= N) continue;
#pragma unroll
      for (int j = 0; j < 4; ++j) {
        int mg = m0 + wr * 64 + m * 16 + rl + j;
        float v = acc[m][n][j];
        if constexpr (MODE == 0) {
          ((bf16*)out)[(long)mg * DM + ng] = (bf16)(v + cb1[ng]);
        } else if constexpr (MODE == 2) {
          ((bf16*)out)[((long)bz << 20) + ((long)mg << 10) + ng] = (bf16)v;
        } else if constexpr (MODE == 7) {
          ((float*)out)[((long)bz << 20) + ((long)mg << 10) + ng] =
              __expf(fmaf(v, SCALE, cb2[(bz << 10) + ng]));
        } else if constexpr (MODE == 8) {
          ((bf16*)out)[(long)((bz >> 2) * SEQ + mg) * DM + (bz & 3) * HD + ng] =
              (bf16)(v * cb2[(bz << 10) + mg]);
        } else if constexpr (MODE == 5) {
          ((bf16*)out)[(long)((bz >> 2) * SEQ + mg) * DM + (bz & 3) * HD + ng] = (bf16)v;
        } else if constexpr (MODE == 6) {
          if (ng < DM) {
            ((bf16*)out)[(long)mg * DM + ng] = (bf16)(v + cb1[ng]);
          } else {
            int d = ng - DM;
            int b = mg >> 10, s = mg & 1023;
            ((bf16*)out2)[((long)(b * DM + d) << 10) + s] = (bf16)(v + cb2[d]);
          }
        } else {
          long o = (long)mg * DM + ng;
          ((float*)out)[o] = v + cb1[ng] + resid[o];
        }
      }
    }
  }
}

// ---------------- layernorm (one wave per row of 768, in place) ----------------
__global__ __launch_bounds__(256) void layernorm_rows(float* x, const float* __restrict__ gam,
                                                      const float* __restrict__ bet) {
  int row = blockIdx.x * 4 + (threadIdx.x >> 6);
  int lane = threadIdx.x & 63;
  float* r = x + (long)row * DM;
  f32x4 v[3];
#pragma unroll
  for (int i = 0; i < 3; ++i) v[i] = *(const f32x4*)&r[i * 256 + lane * 4];
  float s = 0.0f, ss = 0.0f;
#pragma unroll
  for (int i = 0; i < 3; ++i)
#pragma unroll
    for (int j = 0; j < 4; ++j) {
      s += v[i][j];
      ss += v[i][j] * v[i][j];
    }
  for (int d = 1; d < 64; d <<= 1) {
    s += __shfl_xor(s, d);
    ss += __shfl_xor(ss, d);
  }
  float mu = s * (1.0f / 768.0f);
  float var = ss * (1.0f / 768.0f) - mu * mu;
  float rs = 1.0f / sqrtf(var + 1e-5f);
#pragma unroll
  for (int i = 0; i < 3; ++i) {
#pragma unroll
    for (int j = 0; j < 4; ++j) {
      int c = i * 256 + lane * 4 + j;
      v[i][j] = (v[i][j] - mu) * rs * gam[c] + bet[c];
    }
    *(f32x4*)&r[i * 256 + lane * 4] = v[i];
  }
}

// ---------------- launcher ----------------
extern "C" void kernel_launch(void* const* d_in, const int* in_sizes, int n_in,
                              void* d_out, int out_size, void* d_ws, size_t ws_size,
                              hipStream_t stream) {
  const float* Xd = (const float*)d_in[0];
  const float* Xb = (const float*)d_in[1];
  const float* Wq = (const float*)d_in[2];
  const float* bq = (const float*)d_in[3];
  const float* Wk = (const float*)d_in[4];
  const float* bk = (const float*)d_in[5];
  const float* Wv = (const float*)d_in[6];
  const float* bv = (const float*)d_in[7];
  const float* Wb1 = (const float*)d_in[8];
  const float* bb1 = (const float*)d_in[9];
  const float* Wb2 = (const float*)d_in[10];
  const float* bb2 = (const float*)d_in[11];
  const float* Wo = (const float*)d_in[12];
  const float* bo = (const float*)d_in[13];
  const float* lng = (const float*)d_in[14];
  const float* lnb = (const float*)d_in[15];

  float* y = (float*)d_out;                  // 8192*768 f32
  float* attn = y + (long)MROWS * DM;        // 32*1024*1024 f32

  char* w = (char*)d_ws;
  bf16* Xd_bf = (bf16*)w; w += (long)MROWS * DM * 2;   // later reused as ctx
  bf16* Xb_bf = (bf16*)w; w += (long)MROWS * DB * 2;
  bf16* WqvT = (bf16*)w; w += (long)2 * DM * DM * 2;   // [1536][768]
  bf16* WkT = (bf16*)w; w += (long)DM * DB * 2;
  bf16* WoT = (bf16*)w; w += (long)DM * DM * 2;
  bf16* Qb = (bf16*)w; w += (long)MROWS * DM * 2;
  bf16* Kb = (bf16*)w; w += (long)MROWS * DM * 2;
  bf16* VTb = (bf16*)w; w += (long)MROWS * DM * 2;
  float* biasarr = (float*)w; w += (long)BATCH * NHEADS * SEQ * 4;
  float* part = (float*)w; w += (long)32 * SEQ * 16 * 4;   // 2 MB partials
  float* inv = (float*)w; w += (long)32 * SEQ * 4;         // 128 KB
  bf16* Sb = (bf16*)w; w += (long)32 * SEQ * SEQ * 2;      // 64 MB E buffer
  const bool useS = ((size_t)(w - (char*)d_ws)) <= ws_size;
  bf16* ctxb = Xd_bf;  // Xd_bf dead after QV projection; reuse for ctx

  dim3 blk(256);
  // fused prologue: cvt Xd, cvt Xb, bias MLP, weight transposes
  prologue<<<13792, blk, 0, stream>>>(Xd, Xd_bf, Xb, Xb_bf, Wq, Wv, Wk, Wo,
                                      WqvT, WqvT + (long)DM * DM, WkT, WoT,
                                      Wb1, bb1, Wb2, bb2, biasarr);

  // K = Xb @ Wk + bk
  gemm_bt<0><<<dim3(6, 64, 1), blk, 0, stream>>>(Xb_bf, DB, WkT, DB, nullptr, MROWS, DM, DB,
                                                 bk, nullptr, nullptr, Kb, nullptr);
  // [Q | V] = Xd @ [Wq | Wv]: Q natural -> Qb, V scatter-transposed -> VTb
  gemm_bt<6><<<dim3(12, 64, 1), blk, 0, stream>>>(Xd_bf, DM, WqvT, DM, nullptr, MROWS, 2 * DM, DM,
                                                  bq, bv, nullptr, Qb, VTb);
  if (useS) {
    // E = exp(QK^T*scale + bias) bf16 + row-partials
    gemm_bt<2><<<2048, blk, 0, stream>>>(Qb, DM, Kb, DM, nullptr, SEQ, SEQ, HD,
                                         nullptr, biasarr, nullptr, Sb, part);
    make_inv<<<128, blk, 0, stream>>>(part, inv);
    // PV: gld_lds raw E, attn f32 written from LDS (k-split by bx), ctx = acc*inv
    gemm_bt<8><<<512, blk, 0, stream>>>(Sb, SEQ, VTb, SEQ, nullptr, SEQ, HD, SEQ,
                                        nullptr, inv, nullptr, ctxb, attn);
  } else {
    gemm_bt<7><<<2048, blk, 0, stream>>>(Qb, DM, Kb, DM, nullptr, SEQ, SEQ, HD,
                                         nullptr, biasarr, nullptr, attn, nullptr);
    rowsum_scale_f32<<<8192, blk, 0, stream>>>(attn);
    gemm_bt<5><<<512, blk, 0, stream>>>(nullptr, SEQ, VTb, SEQ, attn, SEQ, HD, SEQ,
                                        nullptr, nullptr, nullptr, ctxb, nullptr);
  }
  // x = ctx @ Wo + bo + resid -> y region, then LN in place
  gemm_bt<4><<<dim3(6, 64, 1), blk, 0, stream>>>(ctxb, DM, WoT, DM, nullptr, MROWS, DM, DM,
                                                 bo, nullptr, Xd, y, nullptr);
  layernorm_rows<<<2048, 256, 0, stream>>>(y, lng, lnb);
}